// Round 5
// baseline (779.989 us; speedup 1.0000x reference)
//
#include <hip/hip_runtime.h>
#include <hip/hip_bf16.h>

#define D_ 1024
#define T_ 2048
#define B_ 4
#define H_ 16
#define HS_ 64
#define DFF_ 4096
#define M_TOT 8192  // B*T

typedef short s8v __attribute__((ext_vector_type(8)));
typedef float f4v __attribute__((ext_vector_type(4)));
typedef float f16v __attribute__((ext_vector_type(16)));
typedef unsigned int u32;

__device__ __forceinline__ void gll16(const void* g, void* l) {
  __builtin_amdgcn_global_load_lds(
      (__attribute__((address_space(1))) void*)(g),
      (__attribute__((address_space(3))) void*)(l), 16, 0, 0);
}

__device__ __forceinline__ u32 cvt_pk_bf16(float lo, float hi) {
  u32 r;
  asm("v_cvt_pk_bf16_f32 %0, %1, %2" : "=v"(r) : "v"(lo), "v"(hi));
  return r;
}

// ---------------- weight transpose+cast: src fp32 (R,C) -> dst bf16 (C,R), dst ld = R
__global__ __launch_bounds__(256) void transpose_cast_kernel(
    const float* __restrict__ src, __hip_bfloat16* __restrict__ dst,
    int R, int C, int row_base) {
  src += (size_t)blockIdx.z * R * C;
  row_base += blockIdx.z * C;
  __shared__ float tile[32][33];
  int c0 = blockIdx.x * 32, r0 = blockIdx.y * 32;
  int tx = threadIdx.x, ty = threadIdx.y;  // (32, 8)
#pragma unroll
  for (int i = 0; i < 4; ++i)
    tile[ty + i * 8][tx] = src[(size_t)(r0 + ty + i * 8) * C + c0 + tx];
  __syncthreads();
#pragma unroll
  for (int i = 0; i < 4; ++i)
    dst[(size_t)(row_base + c0 + ty + i * 8) * R + r0 + tx] =
        __float2bfloat16(tile[tx][ty + i * 8]);
}

// ---------------- V transpose per head: (b,h,T,HS) -> (b,h,HS,T), bf16
__global__ __launch_bounds__(256) void transpose_v_kernel(
    const __hip_bfloat16* __restrict__ Vb, __hip_bfloat16* __restrict__ Vt) {
  const int bh = blockIdx.y;
  const int t0 = blockIdx.x * 64;
  __shared__ short tile[64][72];
  const int tid = threadIdx.x;
  const int r = tid >> 2, cg = tid & 3;
  const __hip_bfloat16* src = Vb + ((size_t)bh * T_ + t0 + r) * HS_ + cg * 16;
  s8v v0 = *(const s8v*)(src);
  s8v v1 = *(const s8v*)(src + 8);
  *(s8v*)&tile[r][cg * 16] = v0;
  *(s8v*)&tile[r][cg * 16 + 8] = v1;
  __syncthreads();
  const int hs = r;
  short o0[8], o1[8];
#pragma unroll
  for (int k2 = 0; k2 < 8; ++k2) o0[k2] = tile[cg * 16 + k2][hs];
#pragma unroll
  for (int k2 = 0; k2 < 8; ++k2) o1[k2] = tile[cg * 16 + 8 + k2][hs];
  __hip_bfloat16* dst = Vt + ((size_t)bh * HS_ + hs) * T_ + t0 + cg * 16;
  *(s8v*)dst = *(s8v*)o0;
  *(s8v*)(dst + 8) = *(s8v*)o1;
}

// ---------------- LayerNorm: fp32 row (1024) -> bf16 row
__global__ __launch_bounds__(256) void ln_kernel(
    const float* __restrict__ x, const float* __restrict__ g,
    const float* __restrict__ be, __hip_bfloat16* __restrict__ out) {
  int row = blockIdx.x;
  int t = threadIdx.x;
  float4 v = ((const float4*)(x + (size_t)row * D_))[t];
  float s = v.x + v.y + v.z + v.w;
  float ss = v.x * v.x + v.y * v.y + v.z * v.z + v.w * v.w;
#pragma unroll
  for (int o = 1; o < 64; o <<= 1) { s += __shfl_xor(s, o); ss += __shfl_xor(ss, o); }
  __shared__ float rs[4], rss[4];
  int w = t >> 6, l = t & 63;
  if (l == 0) { rs[w] = s; rss[w] = ss; }
  __syncthreads();
  s = rs[0] + rs[1] + rs[2] + rs[3];
  ss = rss[0] + rss[1] + rss[2] + rss[3];
  float mu = s * (1.f / D_);
  float var = ss * (1.f / D_) - mu * mu;
  float r = rsqrtf(var + 1e-5f);
  float4 gv = ((const float4*)g)[t];
  float4 bv = ((const float4*)be)[t];
  union { ushort4 u; __hip_bfloat16 h[4]; } pk;
  pk.h[0] = __float2bfloat16((v.x - mu) * r * gv.x + bv.x);
  pk.h[1] = __float2bfloat16((v.y - mu) * r * gv.y + bv.y);
  pk.h[2] = __float2bfloat16((v.z - mu) * r * gv.z + bv.z);
  pk.h[3] = __float2bfloat16((v.w - mu) * r * gv.w + bv.w);
  ((ushort4*)(out + (size_t)row * D_))[t] = pk.u;
}

// ---------------- GEMM C = A(M,K) * Bt(N,K)^T, bf16 in, epilogues:
// EPI 0: scatter to Q,K,V (B,H,T,HS) bf16 (p0,p1,p2); Q pre-scaled by 0.125*log2e
// EPI 1: p0(fp32) = res + C + bias
// EPI 2: p0(bf16) = relu(C + bias)
template <int EPI>
__global__ __launch_bounds__(256) void gemm_bt_kernel(
    const __hip_bfloat16* __restrict__ A, const __hip_bfloat16* __restrict__ Bt,
    int M, int N, int K,
    void* __restrict__ p0, void* __restrict__ p1, void* __restrict__ p2,
    const float* __restrict__ bias, const float* __restrict__ res) {
  __shared__ short sA[128 * 32], sB[128 * 32];
  // XCD-aware bijective swizzle (grids are %8==0): XCD x owns a contiguous chunk.
  const int gdx = gridDim.x;
  const int nwg = gdx * gridDim.y;
  const int orig = blockIdx.y * gdx + blockIdx.x;
  const int swz = ((orig & 7) * (nwg >> 3)) + (orig >> 3);
  const int m0 = (swz / gdx) * 128, n0 = (swz % gdx) * 128;
  const int t = threadIdx.x, l = t & 63, w = t >> 6;
  const int wr = w >> 1, wc = w & 1, lg = l >> 4, lo = l & 15;
  f4v acc[4][4];
#pragma unroll
  for (int m = 0; m < 4; ++m)
#pragma unroll
    for (int n = 0; n < 4; ++n) acc[m][n] = (f4v){0.f, 0.f, 0.f, 0.f};
  const int nkt = K >> 5;
  for (int kt = 0; kt < nkt; ++kt) {
    if (kt) __syncthreads();
#pragma unroll
    for (int j = 0; j < 2; ++j) {
      int i = j * 256 + t;
      int row = i >> 2, kc = i & 3;
      gll16(A + (size_t)(m0 + row) * K + kt * 32 + kc * 8, (char*)sA + i * 16);
      gll16(Bt + (size_t)(n0 + row) * K + kt * 32 + kc * 8, (char*)sB + i * 16);
    }
    __syncthreads();
    s8v af[4], bf[4];
#pragma unroll
    for (int m = 0; m < 4; ++m)
      af[m] = *(const s8v*)((const char*)sA + (wr * 64 + m * 16 + lo) * 64 + lg * 16);
#pragma unroll
    for (int n = 0; n < 4; ++n)
      bf[n] = *(const s8v*)((const char*)sB + (wc * 64 + n * 16 + lo) * 64 + lg * 16);
#pragma unroll
    for (int m = 0; m < 4; ++m)
#pragma unroll
      for (int n = 0; n < 4; ++n)
        acc[m][n] = __builtin_amdgcn_mfma_f32_16x16x32_bf16(af[m], bf[n], acc[m][n], 0, 0, 0);
  }
  // epilogue
#pragma unroll
  for (int mi = 0; mi < 4; ++mi)
#pragma unroll
    for (int j = 0; j < 4; ++j) {
      int mg = m0 + wr * 64 + mi * 16 + lg * 4 + j;
#pragma unroll
      for (int ni = 0; ni < 4; ++ni) {
        int ng = n0 + wc * 64 + ni * 16 + lo;
        float v = acc[mi][ni][j];
        if constexpr (EPI == 0) {
          int wi = ng >> 10, within = ng & 1023, hh = within >> 6, hs = within & 63;
          __hip_bfloat16* dst = (wi == 0) ? (__hip_bfloat16*)p0
                               : (wi == 1) ? (__hip_bfloat16*)p1
                                           : (__hip_bfloat16*)p2;
          float vs = (wi == 0) ? v * 0.18033688f : v;  // fold 0.125*log2(e) into Q
          int b = mg >> 11, tt = mg & 2047;
          dst[(((size_t)(b * H_ + hh)) * T_ + tt) * HS_ + hs] = __float2bfloat16(vs);
        } else if constexpr (EPI == 1) {
          ((float*)p0)[(size_t)mg * N + ng] = res[(size_t)mg * N + ng] + v + bias[ng];
        } else {
          float y = v + bias[ng];
          y = y > 0.f ? y : 0.f;
          ((__hip_bfloat16*)p0)[(size_t)mg * N + ng] = __float2bfloat16(y);
        }
      }
    }
}

// ---------------- causal flash attention, swapped-QK^T (m214 structure).
// Per wave: 32 q-rows, 32x32x16 MFMA. S^T = mfma(K,Q): lane&31 = q-row,
// regs span KV (lane-local reduction axis). P assembled in-register via
// cvt_pk + shfl_xor(32); no P LDS round-trip. Defer-rescale THR=8 (exp2 dom).
template <bool MASK>
__device__ __forceinline__ void attn_step32(
    int s0, int qw, int q, int hi,
    const short* __restrict__ sKb, const short* __restrict__ sVb,
    const s8v (&qf)[4], f16v (&acc)[2], float& m, float& ssum) {
  // S^T = K * Q^T over 2 KV-subtiles of 32
  f16v sfr[2];
#pragma unroll
  for (int s = 0; s < 2; ++s) {
#pragma unroll
    for (int r = 0; r < 16; ++r) sfr[s][r] = 0.f;
    const int row = s * 32 + q;
#pragma unroll
    for (int kc = 0; kc < 4; ++kc) {
      const int slot = (kc * 2 + hi) ^ (row & 7);
      s8v kfr = *(const s8v*)((const char*)sKb + row * 128 + slot * 16);
      sfr[s] = __builtin_amdgcn_mfma_f32_32x32x16_bf16(kfr, qf[kc], sfr[s], 0, 0, 0);
    }
  }
  // lane holds S[q][kv] for 32 of 64 kv (partner lane has the rest)
  float p[2][16];
#pragma unroll
  for (int s = 0; s < 2; ++s)
#pragma unroll
    for (int r = 0; r < 16; ++r) {
      float v = sfr[s][r];
      if (MASK) {
        int kv = s0 + s * 32 + (r & 3) + 8 * (r >> 2) + 4 * hi;
        v = (kv <= qw + q) ? v : -3e38f;
      }
      p[s][r] = v;
    }
  float pm = p[0][0];
#pragma unroll
  for (int s = 0; s < 2; ++s)
#pragma unroll
    for (int r = 0; r < 16; ++r) pm = fmaxf(pm, p[s][r]);
  pm = fmaxf(pm, __shfl_xor(pm, 32));
  if (!__all(pm <= m + 8.f)) {  // defer-rescale (T13)
    float mnew = fmaxf(m, pm);
    float sc = exp2f(m - mnew);
    m = mnew;
    ssum *= sc;
#pragma unroll
    for (int r = 0; r < 16; ++r) {
      float scr = __shfl(sc, (r & 3) + 8 * (r >> 2) + 4 * hi);
      acc[0][r] *= scr;
      acc[1][r] *= scr;
    }
  }
  float ls = 0.f;
#pragma unroll
  for (int s = 0; s < 2; ++s)
#pragma unroll
    for (int r = 0; r < 16; ++r) {
      float e = exp2f(p[s][r] - m);
      p[s][r] = e;
      ls += e;
    }
  ssum += ls + __shfl_xor(ls, 32);
  // pack P -> 4 A-frags (k-chunks of 16 KV): own half + partner half (T12)
  union { u32 u[4]; s8v v; } pa[4];
#pragma unroll
  for (int c = 0; c < 4; ++c) {
    const int s = c >> 1;
    const int bofs = (c & 1) * 8;
    const int og = bofs + 4 * hi, sg = bofs + 4 - 4 * hi;
    u32 own0 = cvt_pk_bf16(p[s][og + 0], p[s][og + 1]);
    u32 own1 = cvt_pk_bf16(p[s][og + 2], p[s][og + 3]);
    u32 snd0 = cvt_pk_bf16(p[s][sg + 0], p[s][sg + 1]);
    u32 snd1 = cvt_pk_bf16(p[s][sg + 2], p[s][sg + 3]);
    u32 rcv0 = (u32)__shfl_xor((int)snd0, 32);
    u32 rcv1 = (u32)__shfl_xor((int)snd1, 32);
    pa[c].u[0] = hi ? rcv0 : own0;
    pa[c].u[1] = hi ? rcv1 : own1;
    pa[c].u[2] = hi ? own0 : rcv0;
    pa[c].u[3] = hi ? own1 : rcv1;
  }
  // O += P * V  (B-frag from V^T tile: lane&31 = hs)
#pragma unroll
  for (int n = 0; n < 2; ++n) {
    const int row = n * 32 + q;
#pragma unroll
    for (int c = 0; c < 4; ++c) {
      const int slot = (c * 2 + hi) ^ (row & 7);
      s8v vfr = *(const s8v*)((const char*)sVb + row * 128 + slot * 16);
      acc[n] = __builtin_amdgcn_mfma_f32_32x32x16_bf16(pa[c].v, vfr, acc[n], 0, 0, 0);
    }
  }
}

// grid: (8, B*H); block 256 = 4 waves x 32 q-rows. Paired q-tiles (i, 15-i):
// equal causal work (34 KV-64 steps) across all 512 blocks.
__global__ __launch_bounds__(256) void attn_kernel(
    const __hip_bfloat16* __restrict__ Q, const __hip_bfloat16* __restrict__ K,
    const __hip_bfloat16* __restrict__ Vt, __hip_bfloat16* __restrict__ O) {
  const int bh = blockIdx.y;
  const int t = threadIdx.x, w = t >> 6, l = t & 63;
  const int q = l & 31, hi = l >> 5;
  const size_t kbase = (size_t)bh * T_ * HS_;  // Q,K: [T][HS]
  const size_t vbase = (size_t)bh * HS_ * T_;  // Vt:  [HS][T]
  __shared__ short sK[2][64 * 64];
  __shared__ short sV[2][64 * 64];
  const int b = bh >> 4, hh = bh & 15;
  for (int pass = 0; pass < 2; ++pass) {
    const int tile = pass ? (15 - (int)blockIdx.x) : (int)blockIdx.x;
    const int q0 = tile * 128;
    const int qw = q0 + w * 32;
    s8v qf[4];  // B-frag: lane&31 = q-row, cols = hi*8+e per k-chunk
#pragma unroll
    for (int kc = 0; kc < 4; ++kc)
      qf[kc] = *(const s8v*)(Q + kbase + (size_t)(qw + q) * HS_ + kc * 16 + hi * 8);
    f16v acc[2];
#pragma unroll
    for (int n = 0; n < 2; ++n)
#pragma unroll
      for (int r = 0; r < 16; ++r) acc[n][r] = 0.f;
    float m = -3e38f, ssum = 0.f;
    const int nst = q0 / 64 + 2;
    // stage K[64][64] and Vt[64][64] via gll16, pre-swizzled global source
    auto stg = [&](int st) {
      int bi = st & 1;
      int s0 = st * 64;
#pragma unroll
      for (int r = 0; r < 2; ++r) {
        int i = r * 256 + t;
        int row = i >> 3, sl = i & 7;
        int sls = sl ^ (row & 7);
        gll16(K + kbase + (size_t)(s0 + row) * HS_ + sls * 8,
              (char*)sK[bi] + i * 16);
        gll16(Vt + vbase + (size_t)row * T_ + s0 + sls * 8,
              (char*)sV[bi] + i * 16);
      }
    };
    stg(0);
    __syncthreads();
    for (int st = 0; st < nst; ++st) {
      if (st + 1 < nst) stg(st + 1);  // prefetch flies under compute
      const int s0 = st * 64;
      if (s0 <= qw + 31) {  // skip fully-masked steps for this wave
        if (st < nst - 2)
          attn_step32<false>(s0, qw, q, hi, sK[st & 1], sV[st & 1], qf, acc, m, ssum);
        else
          attn_step32<true>(s0, qw, q, hi, sK[st & 1], sV[st & 1], qf, acc, m, ssum);
      }
      __syncthreads();  // drains prefetch vmcnt + all waves' LDS reads
    }
    // epilogue: O[(b*T + qw+rm)*D + hh*64 + n*32 + q]
    float inv = 1.f / ssum;
#pragma unroll
    for (int r = 0; r < 16; ++r) {
      const int rm = (r & 3) + 8 * (r >> 2) + 4 * hi;
      float iv = __shfl(inv, rm);
      const size_t orow = ((size_t)b * T_ + qw + rm) * D_ + hh * HS_;
      O[orow + q] = __float2bfloat16(acc[0][r] * iv);
      O[orow + 32 + q] = __float2bfloat16(acc[1][r] * iv);
    }
  }
}

extern "C" void kernel_launch(void* const* d_in, const int* in_sizes, int n_in,
                              void* d_out, int out_size, void* d_ws, size_t ws_size,
                              hipStream_t stream) {
  const float* x   = (const float*)d_in[0];
  const float* wq  = (const float*)d_in[1];
  const float* wk  = (const float*)d_in[2];
  const float* wv  = (const float*)d_in[3];
  const float* wo  = (const float*)d_in[4];
  const float* bo  = (const float*)d_in[5];
  const float* w1  = (const float*)d_in[6];
  const float* b1  = (const float*)d_in[7];
  const float* w2  = (const float*)d_in[8];
  const float* b2  = (const float*)d_in[9];
  const float* g1  = (const float*)d_in[10];
  const float* be1 = (const float*)d_in[11];
  const float* g2  = (const float*)d_in[12];
  const float* be2 = (const float*)d_in[13];
  float* out = (float*)d_out;

  char* ws = (char*)d_ws;
  auto alloc = [&](size_t bytes) {
    char* p = ws;
    ws += (bytes + 255) & ~(size_t)255;
    return p;
  };
  __hip_bfloat16* qkvT  = (__hip_bfloat16*)alloc((size_t)3 * D_ * D_ * 2);
  __hip_bfloat16* woT   = (__hip_bfloat16*)alloc((size_t)D_ * D_ * 2);
  __hip_bfloat16* w1T   = (__hip_bfloat16*)alloc((size_t)DFF_ * D_ * 2);
  __hip_bfloat16* w2T   = (__hip_bfloat16*)alloc((size_t)D_ * DFF_ * 2);
  __hip_bfloat16* hbuf  = (__hip_bfloat16*)alloc((size_t)M_TOT * D_ * 2);
  float*          x1    = (float*)alloc((size_t)M_TOT * D_ * 4);
  // Vtb aliases x1: Vtb lives [post-QKV .. attn], x1 lives [out-proj .. FFN2].
  __hip_bfloat16* Vtb   = (__hip_bfloat16*)x1;
  // Aliased region: Q/K/V/attn (4 x 16MB) live until out-proj; ffb (64MB)
  // only live after out-proj.
  char* aliased = alloc((size_t)M_TOT * DFF_ * 2);
  __hip_bfloat16* Qb    = (__hip_bfloat16*)(aliased);
  __hip_bfloat16* Kb    = (__hip_bfloat16*)(aliased + (size_t)M_TOT * D_ * 2);
  __hip_bfloat16* Vb    = (__hip_bfloat16*)(aliased + (size_t)M_TOT * D_ * 4);
  __hip_bfloat16* attnb = (__hip_bfloat16*)(aliased + (size_t)M_TOT * D_ * 6);
  __hip_bfloat16* ffb   = (__hip_bfloat16*)(aliased);

  dim3 tb(32, 8);
  // weight prep (bf16, transposed)
  transpose_cast_kernel<<<dim3(2, 32, 16), tb, 0, stream>>>(wq, qkvT, D_, HS_, 0);
  transpose_cast_kernel<<<dim3(2, 32, 16), tb, 0, stream>>>(wk, qkvT, D_, HS_, 1024);
  transpose_cast_kernel<<<dim3(2, 32, 16), tb, 0, stream>>>(wv, qkvT, D_, HS_, 2048);
  transpose_cast_kernel<<<dim3(32, 32, 1), tb, 0, stream>>>(wo, woT, D_, D_, 0);
  transpose_cast_kernel<<<dim3(128, 32, 1), tb, 0, stream>>>(w1, w1T, D_, DFF_, 0);
  transpose_cast_kernel<<<dim3(32, 128, 1), tb, 0, stream>>>(w2, w2T, DFF_, D_, 0);
  // LN1
  ln_kernel<<<M_TOT, 256, 0, stream>>>(x, g1, be1, hbuf);
  // QKV
  gemm_bt_kernel<0><<<dim3(24, 64), 256, 0, stream>>>(hbuf, qkvT, M_TOT, 3 * D_, D_,
                                                      Qb, Kb, Vb, nullptr, nullptr);
  // V -> V^T (per head)
  transpose_v_kernel<<<dim3(32, 64), 256, 0, stream>>>(Vb, Vtb);
  // attention
  attn_kernel<<<dim3(8, 64), 256, 0, stream>>>(Qb, Kb, Vtb, attnb);
  // out proj + residual
  gemm_bt_kernel<1><<<dim3(8, 64), 256, 0, stream>>>(attnb, woT, M_TOT, D_, D_,
                                                     x1, nullptr, nullptr, bo, x);
  // LN2
  ln_kernel<<<M_TOT, 256, 0, stream>>>(x1, g2, be2, hbuf);
  // FFN1 (relu)
  gemm_bt_kernel<2><<<dim3(32, 64), 256, 0, stream>>>(hbuf, w1T, M_TOT, DFF_, D_,
                                                      ffb, nullptr, nullptr, b1, nullptr);
  // FFN2 + residual -> out
  gemm_bt_kernel<1><<<dim3(8, 64), 256, 0, stream>>>(ffb, w2T, M_TOT, D_, DFF_,
                                                     out, nullptr, nullptr, b2, x1);
}

// Round 6
// 688.416 us; speedup vs baseline: 1.1330x; 1.1330x over previous
//
#include <hip/hip_runtime.h>
#include <hip/hip_bf16.h>

#define D_ 1024
#define T_ 2048
#define B_ 4
#define H_ 16
#define HS_ 64
#define DFF_ 4096
#define M_TOT 8192  // B*T

typedef short s8v __attribute__((ext_vector_type(8)));
typedef float f4v __attribute__((ext_vector_type(4)));

__device__ __forceinline__ void gll16(const void* g, void* l) {
  __builtin_amdgcn_global_load_lds(
      (__attribute__((address_space(1))) void*)(g),
      (__attribute__((address_space(3))) void*)(l), 16, 0, 0);
}

__device__ __forceinline__ short f2b(float f) {
  __hip_bfloat16 h = __float2bfloat16(f);
  short s; __builtin_memcpy(&s, &h, 2); return s;
}

// ---------------- weight transpose+cast: src fp32 (R,C) -> dst bf16 (C,R), dst ld = R
__global__ __launch_bounds__(256) void transpose_cast_kernel(
    const float* __restrict__ src, __hip_bfloat16* __restrict__ dst,
    int R, int C, int row_base) {
  src += (size_t)blockIdx.z * R * C;
  row_base += blockIdx.z * C;
  __shared__ float tile[32][33];
  int c0 = blockIdx.x * 32, r0 = blockIdx.y * 32;
  int tx = threadIdx.x, ty = threadIdx.y;  // (32, 8)
#pragma unroll
  for (int i = 0; i < 4; ++i)
    tile[ty + i * 8][tx] = src[(size_t)(r0 + ty + i * 8) * C + c0 + tx];
  __syncthreads();
#pragma unroll
  for (int i = 0; i < 4; ++i)
    dst[(size_t)(row_base + c0 + ty + i * 8) * R + r0 + tx] =
        __float2bfloat16(tile[tx][ty + i * 8]);
}

// ---------------- V transpose per head: (b,h,T,HS) -> (b,h,HS,T), bf16
__global__ __launch_bounds__(256) void transpose_v_kernel(
    const __hip_bfloat16* __restrict__ Vb, __hip_bfloat16* __restrict__ Vt) {
  const int bh = blockIdx.y;
  const int t0 = blockIdx.x * 64;
  __shared__ short tile[64][72];
  const int tid = threadIdx.x;
  const int r = tid >> 2, cg = tid & 3;
  const __hip_bfloat16* src = Vb + ((size_t)bh * T_ + t0 + r) * HS_ + cg * 16;
  s8v v0 = *(const s8v*)(src);
  s8v v1 = *(const s8v*)(src + 8);
  *(s8v*)&tile[r][cg * 16] = v0;
  *(s8v*)&tile[r][cg * 16 + 8] = v1;
  __syncthreads();
  const int hs = r;
  short o0[8], o1[8];
#pragma unroll
  for (int k2 = 0; k2 < 8; ++k2) o0[k2] = tile[cg * 16 + k2][hs];
#pragma unroll
  for (int k2 = 0; k2 < 8; ++k2) o1[k2] = tile[cg * 16 + 8 + k2][hs];
  __hip_bfloat16* dst = Vt + ((size_t)bh * HS_ + hs) * T_ + t0 + cg * 16;
  *(s8v*)dst = *(s8v*)o0;
  *(s8v*)(dst + 8) = *(s8v*)o1;
}

// ---------------- LayerNorm: fp32 row (1024) -> bf16 row
__global__ __launch_bounds__(256) void ln_kernel(
    const float* __restrict__ x, const float* __restrict__ g,
    const float* __restrict__ be, __hip_bfloat16* __restrict__ out) {
  int row = blockIdx.x;
  int t = threadIdx.x;
  float4 v = ((const float4*)(x + (size_t)row * D_))[t];
  float s = v.x + v.y + v.z + v.w;
  float ss = v.x * v.x + v.y * v.y + v.z * v.z + v.w * v.w;
#pragma unroll
  for (int o = 1; o < 64; o <<= 1) { s += __shfl_xor(s, o); ss += __shfl_xor(ss, o); }
  __shared__ float rs[4], rss[4];
  int w = t >> 6, l = t & 63;
  if (l == 0) { rs[w] = s; rss[w] = ss; }
  __syncthreads();
  s = rs[0] + rs[1] + rs[2] + rs[3];
  ss = rss[0] + rss[1] + rss[2] + rss[3];
  float mu = s * (1.f / D_);
  float var = ss * (1.f / D_) - mu * mu;
  float r = rsqrtf(var + 1e-5f);
  float4 gv = ((const float4*)g)[t];
  float4 bv = ((const float4*)be)[t];
  union { ushort4 u; __hip_bfloat16 h[4]; } pk;
  pk.h[0] = __float2bfloat16((v.x - mu) * r * gv.x + bv.x);
  pk.h[1] = __float2bfloat16((v.y - mu) * r * gv.y + bv.y);
  pk.h[2] = __float2bfloat16((v.z - mu) * r * gv.z + bv.z);
  pk.h[3] = __float2bfloat16((v.w - mu) * r * gv.w + bv.w);
  ((ushort4*)(out + (size_t)row * D_))[t] = pk.u;
}

// ---------------- GEMM C = A(M,K) * Bt(N,K)^T, bf16 in, 2-phase prefetch:
// stage(t+1) issued BEFORE compute(t); single barrier per K-step (its implicit
// vmcnt(0) lands the prefetch that flew under the MFMAs + protects buf reuse).
// EPI 0: scatter to Q,K,V (B,H,T,HS) bf16 (p0,p1,p2)
// EPI 1: p0(fp32) = res + C + bias
// EPI 2: p0(bf16) = relu(C + bias)
template <int EPI>
__global__ __launch_bounds__(256) void gemm_bt_kernel(
    const __hip_bfloat16* __restrict__ A, const __hip_bfloat16* __restrict__ Bt,
    int M, int N, int K,
    void* __restrict__ p0, void* __restrict__ p1, void* __restrict__ p2,
    const float* __restrict__ bias, const float* __restrict__ res) {
  __shared__ short sA[2][128 * 32], sB[2][128 * 32];
  // XCD-aware bijective swizzle (grids are %8==0): XCD x owns a contiguous chunk.
  const int gdx = gridDim.x;
  const int nwg = gdx * gridDim.y;
  const int orig = blockIdx.y * gdx + blockIdx.x;
  const int swz = ((orig & 7) * (nwg >> 3)) + (orig >> 3);
  const int m0 = (swz / gdx) * 128, n0 = (swz % gdx) * 128;
  const int t = threadIdx.x, l = t & 63, w = t >> 6;
  const int wr = w >> 1, wc = w & 1, lg = l >> 4, lo = l & 15;
  f4v acc[4][4];
#pragma unroll
  for (int m = 0; m < 4; ++m)
#pragma unroll
    for (int n = 0; n < 4; ++n) acc[m][n] = (f4v){0.f, 0.f, 0.f, 0.f};
  const int nkt = K >> 5;
  auto stage = [&](int kt, int bi) {
#pragma unroll
    for (int j = 0; j < 2; ++j) {
      int i = j * 256 + t;
      int row = i >> 2, kc = i & 3;
      gll16(A + (size_t)(m0 + row) * K + kt * 32 + kc * 8, (char*)sA[bi] + i * 16);
      gll16(Bt + (size_t)(n0 + row) * K + kt * 32 + kc * 8, (char*)sB[bi] + i * 16);
    }
  };
  stage(0, 0);
  __syncthreads();  // buf0 ready
  for (int kt = 0; kt < nkt; ++kt) {
    const int bi = kt & 1;
    if (kt + 1 < nkt) stage(kt + 1, bi ^ 1);  // prefetch flies under MFMAs
    s8v af[4], bf[4];
#pragma unroll
    for (int m = 0; m < 4; ++m)
      af[m] = *(const s8v*)((const char*)sA[bi] + (wr * 64 + m * 16 + lo) * 64 + lg * 16);
#pragma unroll
    for (int n = 0; n < 4; ++n)
      bf[n] = *(const s8v*)((const char*)sB[bi] + (wc * 64 + n * 16 + lo) * 64 + lg * 16);
#pragma unroll
    for (int m = 0; m < 4; ++m)
#pragma unroll
      for (int n = 0; n < 4; ++n)
        acc[m][n] = __builtin_amdgcn_mfma_f32_16x16x32_bf16(af[m], bf[n], acc[m][n], 0, 0, 0);
    __syncthreads();  // all reads of buf bi done + prefetch landed
  }
  // epilogue
#pragma unroll
  for (int mi = 0; mi < 4; ++mi)
#pragma unroll
    for (int j = 0; j < 4; ++j) {
      int mg = m0 + wr * 64 + mi * 16 + lg * 4 + j;
#pragma unroll
      for (int ni = 0; ni < 4; ++ni) {
        int ng = n0 + wc * 64 + ni * 16 + lo;
        float v = acc[mi][ni][j];
        if constexpr (EPI == 0) {
          int wi = ng >> 10, within = ng & 1023, hh = within >> 6, hs = within & 63;
          __hip_bfloat16* dst = (wi == 0) ? (__hip_bfloat16*)p0
                               : (wi == 1) ? (__hip_bfloat16*)p1
                                           : (__hip_bfloat16*)p2;
          int b = mg >> 11, tt = mg & 2047;
          dst[(((size_t)(b * H_ + hh)) * T_ + tt) * HS_ + hs] = __float2bfloat16(v);
        } else if constexpr (EPI == 1) {
          ((float*)p0)[(size_t)mg * N + ng] = res[(size_t)mg * N + ng] + v + bias[ng];
        } else {
          float y = v + bias[ng];
          y = y > 0.f ? y : 0.f;
          ((__hip_bfloat16*)p0)[(size_t)mg * N + ng] = __float2bfloat16(y);
        }
      }
    }
}

// ---------------- causal flash attention, KVBLK=64, 2-phase pipelined,
// XOR-swizzled LDS (slot ^= row&7 on 16B slots of 128B rows).  [round-4 verbatim]
template <bool MASK>
__device__ __forceinline__ void attn_step(
    int s0, int qrow, int lg, int lo,
    const short* __restrict__ sKb, const short* __restrict__ sVb,
    short* __restrict__ sPw,
    const s8v (&qf)[2][2], f4v (&acc)[2][4], float (&rmax)[2][4],
    float (&rsum)[2][4]) {
  s8v kf[4][2];
#pragma unroll
  for (int si = 0; si < 4; ++si) {
    int row = si * 16 + lo;
#pragma unroll
    for (int kc = 0; kc < 2; ++kc) {
      int slot = (kc * 4 + lg) ^ (row & 7);
      kf[si][kc] = *(const s8v*)((const char*)sKb + row * 128 + slot * 16);
    }
  }
  f4v sfr[2][4];
#pragma unroll
  for (int mi = 0; mi < 2; ++mi)
#pragma unroll
    for (int si = 0; si < 4; ++si) {
      sfr[mi][si] = (f4v){0.f, 0.f, 0.f, 0.f};
#pragma unroll
      for (int kc = 0; kc < 2; ++kc)
        sfr[mi][si] = __builtin_amdgcn_mfma_f32_16x16x32_bf16(
            qf[mi][kc], kf[si][kc], sfr[mi][si], 0, 0, 0);
    }
  const float c = 0.18033688f;  // 0.125 * log2(e): softmax in exp2 domain
  float p[2][4][4];
#pragma unroll
  for (int mi = 0; mi < 2; ++mi)
#pragma unroll
    for (int si = 0; si < 4; ++si)
#pragma unroll
      for (int j = 0; j < 4; ++j) {
        float vv = sfr[mi][si][j] * c;
        if (MASK) {
          int r = qrow + mi * 16 + lg * 4 + j;
          int s = s0 + si * 16 + lo;
          vv = (s <= r) ? vv : -3e38f;
        }
        p[mi][si][j] = vv;
      }
  float tmax[2][4];
  bool grow = false;
#pragma unroll
  for (int mi = 0; mi < 2; ++mi)
#pragma unroll
    for (int j = 0; j < 4; ++j) {
      float tm = fmaxf(fmaxf(p[mi][0][j], p[mi][1][j]),
                       fmaxf(p[mi][2][j], p[mi][3][j]));
#pragma unroll
      for (int o = 1; o < 16; o <<= 1) tm = fmaxf(tm, __shfl_xor(tm, o));
      tmax[mi][j] = tm;
      grow = grow || (tm > rmax[mi][j]);
    }
  if (__any(grow)) {  // defer-rescale: skip whole block when no row max grew
#pragma unroll
    for (int mi = 0; mi < 2; ++mi)
#pragma unroll
      for (int j = 0; j < 4; ++j) {
        float mnew = fmaxf(rmax[mi][j], tmax[mi][j]);
        float sc = exp2f(rmax[mi][j] - mnew);
        rmax[mi][j] = mnew;
        rsum[mi][j] *= sc;
#pragma unroll
        for (int ni = 0; ni < 4; ++ni) acc[mi][ni][j] *= sc;
      }
  }
#pragma unroll
  for (int mi = 0; mi < 2; ++mi)
#pragma unroll
    for (int j = 0; j < 4; ++j) {
      float m = rmax[mi][j];
      float ls = 0.f;
#pragma unroll
      for (int si = 0; si < 4; ++si) {
        float e = exp2f(p[mi][si][j] - m);
        p[mi][si][j] = e;
        ls += e;
      }
#pragma unroll
      for (int o = 1; o < 16; o <<= 1) ls += __shfl_xor(ls, o);
      rsum[mi][j] += ls;
    }
  // P -> LDS (swizzled), then PV
#pragma unroll
  for (int mi = 0; mi < 2; ++mi)
#pragma unroll
    for (int si = 0; si < 4; ++si)
#pragma unroll
      for (int j = 0; j < 4; ++j) {
        int row = mi * 16 + lg * 4 + j;
        int s = si * 16 + lo;
        int slot = (s >> 3) ^ (row & 7);
        *(short*)((char*)sPw + row * 128 + slot * 16 + (s & 7) * 2) =
            f2b(p[mi][si][j]);
      }
  s8v pa[2][2], vf[4][2];
#pragma unroll
  for (int mi = 0; mi < 2; ++mi) {
    int row = mi * 16 + lo;
#pragma unroll
    for (int sb = 0; sb < 2; ++sb) {
      int slot = (sb * 4 + lg) ^ (row & 7);
      pa[mi][sb] = *(const s8v*)((const char*)sPw + row * 128 + slot * 16);
    }
  }
#pragma unroll
  for (int ni = 0; ni < 4; ++ni) {
    int row = ni * 16 + lo;
#pragma unroll
    for (int sb = 0; sb < 2; ++sb) {
      int slot = (sb * 4 + lg) ^ (row & 7);
      vf[ni][sb] = *(const s8v*)((const char*)sVb + row * 128 + slot * 16);
    }
  }
#pragma unroll
  for (int mi = 0; mi < 2; ++mi)
#pragma unroll
    for (int ni = 0; ni < 4; ++ni)
#pragma unroll
      for (int sb = 0; sb < 2; ++sb)
        acc[mi][ni] = __builtin_amdgcn_mfma_f32_16x16x32_bf16(
            pa[mi][sb], vf[ni][sb], acc[mi][ni], 0, 0, 0);
}

// grid: (8, B*H); block 256 = 4 waves x 32 q-rows. Each block runs paired
// q-tiles (i, 15-i): equal causal work (34 KV steps) across all blocks.
__global__ __launch_bounds__(256) void attn_kernel(
    const __hip_bfloat16* __restrict__ Q, const __hip_bfloat16* __restrict__ K,
    const __hip_bfloat16* __restrict__ Vt, __hip_bfloat16* __restrict__ O) {
  const int bh = blockIdx.y;
  const int t = threadIdx.x, w = t >> 6, l = t & 63, lg = l >> 4, lo = l & 15;
  const size_t kbase = (size_t)bh * T_ * HS_;  // Q,K: [T][HS]
  const size_t vbase = (size_t)bh * HS_ * T_;  // Vt:  [HS][T]
  __shared__ short sK[2][64 * 64];
  __shared__ short sV[2][64 * 64];
  __shared__ short sP[4][32 * 64];
  const int b = bh >> 4, hh = bh & 15;
  for (int pass = 0; pass < 2; ++pass) {
    const int tile = pass ? (15 - (int)blockIdx.x) : (int)blockIdx.x;
    const int q0 = tile * 128;
    const int qrow = q0 + w * 32;
    s8v qf[2][2];
#pragma unroll
    for (int mi = 0; mi < 2; ++mi)
#pragma unroll
      for (int kc = 0; kc < 2; ++kc)
        qf[mi][kc] = *(const s8v*)(Q + kbase +
                                   (size_t)(qrow + mi * 16 + lo) * HS_ +
                                   kc * 32 + lg * 8);
    f4v acc[2][4];
    float rmax[2][4], rsum[2][4];
#pragma unroll
    for (int mi = 0; mi < 2; ++mi) {
#pragma unroll
      for (int ni = 0; ni < 4; ++ni) acc[mi][ni] = (f4v){0.f, 0.f, 0.f, 0.f};
#pragma unroll
      for (int j = 0; j < 4; ++j) { rmax[mi][j] = -3e38f; rsum[mi][j] = 0.f; }
    }
    const int nst = q0 / 64 + 2;
    // stage: gll16 with pre-swizzled global source (inverse of read swizzle)
    auto stg = [&](int st) {
      int bi = st & 1;
      int s0 = st * 64;
#pragma unroll
      for (int r = 0; r < 2; ++r) {
        int i = r * 256 + t;
        int row = i >> 3, sl = i & 7;
        int sls = sl ^ (row & 7);
        gll16(K + kbase + (size_t)(s0 + row) * HS_ + sls * 8,
              (char*)sK[bi] + i * 16);
        gll16(Vt + vbase + (size_t)row * T_ + s0 + sls * 8,
              (char*)sV[bi] + i * 16);
      }
    };
    stg(0);
    __syncthreads();
    for (int st = 0; st < nst; ++st) {
      if (st + 1 < nst) stg(st + 1);  // prefetch flies under compute
      const int s0 = st * 64;
      if (s0 <= qrow + 31) {  // skip fully-masked steps for this wave
        if (st < nst - 2)
          attn_step<false>(s0, qrow, lg, lo, sK[st & 1], sV[st & 1], sP[w],
                           qf, acc, rmax, rsum);
        else
          attn_step<true>(s0, qrow, lg, lo, sK[st & 1], sV[st & 1], sP[w],
                          qf, acc, rmax, rsum);
      }
      __syncthreads();  // drains prefetch vmcnt + all waves' LDS reads
    }
    // epilogue: O[(b*T + r)*D + hh*64 + c]
#pragma unroll
    for (int mi = 0; mi < 2; ++mi)
#pragma unroll
      for (int j = 0; j < 4; ++j) {
        int r = qrow + mi * 16 + lg * 4 + j;
        float inv = 1.f / rsum[mi][j];
#pragma unroll
        for (int ni = 0; ni < 4; ++ni) {
          int cc = ni * 16 + lo;
          O[((size_t)b * T_ + r) * D_ + hh * HS_ + cc] =
              __float2bfloat16(acc[mi][ni][j] * inv);
        }
      }
  }
}

extern "C" void kernel_launch(void* const* d_in, const int* in_sizes, int n_in,
                              void* d_out, int out_size, void* d_ws, size_t ws_size,
                              hipStream_t stream) {
  const float* x   = (const float*)d_in[0];
  const float* wq  = (const float*)d_in[1];
  const float* wk  = (const float*)d_in[2];
  const float* wv  = (const float*)d_in[3];
  const float* wo  = (const float*)d_in[4];
  const float* bo  = (const float*)d_in[5];
  const float* w1  = (const float*)d_in[6];
  const float* b1  = (const float*)d_in[7];
  const float* w2  = (const float*)d_in[8];
  const float* b2  = (const float*)d_in[9];
  const float* g1  = (const float*)d_in[10];
  const float* be1 = (const float*)d_in[11];
  const float* g2  = (const float*)d_in[12];
  const float* be2 = (const float*)d_in[13];
  float* out = (float*)d_out;

  char* ws = (char*)d_ws;
  auto alloc = [&](size_t bytes) {
    char* p = ws;
    ws += (bytes + 255) & ~(size_t)255;
    return p;
  };
  __hip_bfloat16* qkvT  = (__hip_bfloat16*)alloc((size_t)3 * D_ * D_ * 2);
  __hip_bfloat16* woT   = (__hip_bfloat16*)alloc((size_t)D_ * D_ * 2);
  __hip_bfloat16* w1T   = (__hip_bfloat16*)alloc((size_t)DFF_ * D_ * 2);
  __hip_bfloat16* w2T   = (__hip_bfloat16*)alloc((size_t)D_ * DFF_ * 2);
  __hip_bfloat16* hbuf  = (__hip_bfloat16*)alloc((size_t)M_TOT * D_ * 2);
  float*          x1    = (float*)alloc((size_t)M_TOT * D_ * 4);
  // Vtb aliases x1: Vtb lives [post-QKV .. attn], x1 lives [out-proj .. FFN2].
  __hip_bfloat16* Vtb   = (__hip_bfloat16*)x1;
  // Aliased region: Q/K/V/attn (4 x 16MB) live until out-proj; ffb (64MB)
  // only live after out-proj.
  char* aliased = alloc((size_t)M_TOT * DFF_ * 2);
  __hip_bfloat16* Qb    = (__hip_bfloat16*)(aliased);
  __hip_bfloat16* Kb    = (__hip_bfloat16*)(aliased + (size_t)M_TOT * D_ * 2);
  __hip_bfloat16* Vb    = (__hip_bfloat16*)(aliased + (size_t)M_TOT * D_ * 4);
  __hip_bfloat16* attnb = (__hip_bfloat16*)(aliased + (size_t)M_TOT * D_ * 6);
  __hip_bfloat16* ffb   = (__hip_bfloat16*)(aliased);

  dim3 tb(32, 8);
  // weight prep (bf16, transposed)
  transpose_cast_kernel<<<dim3(2, 32, 16), tb, 0, stream>>>(wq, qkvT, D_, HS_, 0);
  transpose_cast_kernel<<<dim3(2, 32, 16), tb, 0, stream>>>(wk, qkvT, D_, HS_, 1024);
  transpose_cast_kernel<<<dim3(2, 32, 16), tb, 0, stream>>>(wv, qkvT, D_, HS_, 2048);
  transpose_cast_kernel<<<dim3(32, 32, 1), tb, 0, stream>>>(wo, woT, D_, D_, 0);
  transpose_cast_kernel<<<dim3(128, 32, 1), tb, 0, stream>>>(w1, w1T, D_, DFF_, 0);
  transpose_cast_kernel<<<dim3(32, 128, 1), tb, 0, stream>>>(w2, w2T, DFF_, D_, 0);
  // LN1
  ln_kernel<<<M_TOT, 256, 0, stream>>>(x, g1, be1, hbuf);
  // QKV
  gemm_bt_kernel<0><<<dim3(24, 64), 256, 0, stream>>>(hbuf, qkvT, M_TOT, 3 * D_, D_,
                                                      Qb, Kb, Vb, nullptr, nullptr);
  // V -> V^T (per head)
  transpose_v_kernel<<<dim3(32, 64), 256, 0, stream>>>(Vb, Vtb);
  // attention
  attn_kernel<<<dim3(8, 64), 256, 0, stream>>>(Qb, Kb, Vtb, attnb);
  // out proj + residual
  gemm_bt_kernel<1><<<dim3(8, 64), 256, 0, stream>>>(attnb, woT, M_TOT, D_, D_,
                                                     x1, nullptr, nullptr, bo, x);
  // LN2
  ln_kernel<<<M_TOT, 256, 0, stream>>>(x1, g2, be2, hbuf);
  // FFN1 (relu)
  gemm_bt_kernel<2><<<dim3(32, 64), 256, 0, stream>>>(hbuf, w1T, M_TOT, DFF_, D_,
                                                      ffb, nullptr, nullptr, b1, nullptr);
  // FFN2 + residual -> out
  gemm_bt_kernel<1><<<dim3(8, 64), 256, 0, stream>>>(ffb, w2T, M_TOT, D_, DFF_,
                                                     out, nullptr, nullptr, b2, x1);
}